// Round 6
// baseline (1768.256 us; speedup 1.0000x reference)
//
#include <hip/hip_runtime.h>
#include <math.h>

// B=32, Cin=64, H=W=56, Cout=128, K=3 pad=1 -> D=576, out (32,128,56,56) fp32
#define B_    32
#define CIN   64
#define HH    56
#define WW    56
#define COUT  128
#define DD    576
#define KC    384            // OpenBLAS kc split (verified R9)
#define LPX   (HH*WW)        // 3136 = 49*64
#define TOTAL (B_*COUT*LPX)
#define NX    (B_*CIN*LPX)   // 6422528
#define PW    58             // padded plane width/height
#define PPL   (PW*PW)        // 3364 words per padded channel plane
#define NXP   (B_*CIN*PPL)   // 6889472 words
#define MARGIN 4e-4f         // worst-case split-bf16 + reorder bound (validated R15-18)

typedef __attribute__((ext_vector_type(8)))  short  short8;
typedef __attribute__((ext_vector_type(16))) float  float16v;

__device__ __forceinline__ unsigned short bf16_rne(float f) {
    unsigned u = __float_as_uint(f);
    unsigned r = u + 0x7FFFu + ((u >> 16) & 1u);
    return (unsigned short)(r >> 16);
}
__device__ __forceinline__ float bf16_to_f(unsigned short h) {
    return __uint_as_float(((unsigned)h) << 16);
}

// ---- bit-exact numpy FLOAT_sin (npyv FMA path) — verified R9 ----
__device__ __forceinline__ float np_sinf(float x) {
#pragma clang fp contract(off)
    const float rint_cvt = 0x1.8p+23f;
    float q = __fmul_rn(x, 0x1.45f306p-1f);
    q = __fadd_rn(q, rint_cvt);
    q = __fsub_rn(q, rint_cvt);
    float r = fmaf(q, -0x1.921fb0p+0f, x);
    r = fmaf(q, -0x1.5110b4p-22f, r);
    r = fmaf(q, -0x1.846988p-48f, r);
    float r2 = __fmul_rn(r, r);
    float s = fmaf(0x1.7d3bbcp-19f, r2, -0x1.a06bbap-13f);
    s = fmaf(s, r2, 0x1.11119ap-7f);
    s = fmaf(s, r2, -0x1.555556p-3f);
    s = __fmul_rn(s, r2);
    s = fmaf(s, r, r);
    float c = fmaf(0x1.98e616p-16f, r2, -0x1.6c06dcp-10f);
    c = fmaf(c, r2, 0x1.55553cp-5f);
    c = fmaf(c, r2, -0.5f);
    c = fmaf(c, r2, 1.0f);
    int iq = (int)q;
    float res = (iq & 1) ? c : s;
    unsigned sgn = ((unsigned)(iq & 2)) << 30;
    return __uint_as_float(__float_as_uint(res) ^ sgn);
}
__device__ __forceinline__ int dec_np(float z) {
    float s = np_sinf(z);
    return (__fmul_rn(s, s) > 0.5f) ? 1 : 0;
}

// ---- merged prep: W -> fragment-major bf16 hi/lo pack, x -> padded 58x58
// planes of (hi | lo<<16) u32 words, borders zero (verified R3/R4/R5) ----
// W dst for (o,k): k18=k/32, kr=k%32, s=kr/16, half=(kr%16)/8, j=kr%8
//   lane = half*32 + (o%32), ot = o/32
//   idx  = (((k18*4 + ot)*2 + s)*64 + lane)*8 + j
__global__ __launch_bounds__(256)
void prep_all(const float* __restrict__ x, const float* __restrict__ W,
              unsigned* __restrict__ xpad,
              unsigned short* __restrict__ Wph, unsigned short* __restrict__ Wpl,
              unsigned* __restrict__ wcount) {
    int i = blockIdx.x * 256 + threadIdx.x;
    if (i == 0) *wcount = 0;
    if (i < COUT * DD) {
        int o = i / DD, k = i - o * DD;
        float w = W[i];
        unsigned short h = bf16_rne(w);
        unsigned short l = bf16_rne(w - bf16_to_f(h));
        int k18 = k >> 5, kr = k & 31;
        int s = (kr >> 4) & 1, half = (kr >> 3) & 1, j = kr & 7;
        int lane = half * 32 + (o & 31);
        int ot = o >> 5;
        unsigned dst = ((((unsigned)(k18 * 4 + ot)) * 2 + s) * 64 + lane) * 8 + j;
        Wph[dst] = h;
        Wpl[dst] = l;
    }
    if (i < NXP) {
        int bc = i / PPL;
        int r  = i - bc * PPL;
        int yy = r / PW;
        int xx = r - yy * PW;
        unsigned v = 0u;
        if (yy >= 1 && yy <= HH && xx >= 1 && xx <= WW) {
            float f = x[(size_t)bc * LPX + (yy - 1) * WW + (xx - 1)];
            unsigned short h = bf16_rne(f);
            unsigned short l = bf16_rne(f - bf16_to_f(h));
            v = (unsigned)h | ((unsigned)l << 16);
        }
        xpad[i] = v;
    }
}

// ---- MFMA conv: barrier-free, LDS-free. 64px x 128out tile, 4 waves.
// Wave w owns o-block w (A via packed Wph/Wpl: coalesced 16B/lane, zero
// duplication). Each lane gathers its OWN B-fragment words from padded
// xpad (R3-verified addressing; lanes lm=0..31 read consecutive pixels ->
// coalesced; the 4 waves' duplicate B reads hit same-CU L1). v_perm repack
// (verified == R5's hw/lw words). No __syncthreads anywhere -> waves are
// independent, latency hidden by TLP + compiler global scheduling.
// Per-acc MFMA order identical to R2/R4/R5 -> bit-identical acc -> MARGIN
// still valid.
#define DOFF(d) ((unsigned)((((d) / 9) * PPL) + ((((d) % 9) / 3) * PW) + (((d) % 9) % 3)))

__global__ __launch_bounds__(256, 4)
void conv_mfma(const unsigned* __restrict__ xpad,
               const unsigned short* __restrict__ Wph,
               const unsigned short* __restrict__ Wpl,
               const float* __restrict__ bias,
               float* __restrict__ out,
               unsigned* __restrict__ wcount,
               unsigned* __restrict__ wlist,
               unsigned wcap) {
    const int tid = threadIdx.x;
    // XCD-chunked bijective swizzle (1568 = 8*196): round-robin dispatch puts
    // orig%8==c on XCD c; give each XCD a contiguous 196-block chunk
    // (= exactly 4 batches of xpad, ~3.4MB -> fits 4MB L2).
    const int bid = (blockIdx.x & 7) * 196 + (blockIdx.x >> 3);
    const int pt0 = bid * 64;            // 64-px tile, never crosses a batch

    const int w    = tid >> 6;           // o-tile (0..3)
    const int lane = tid & 63;
    const int lm   = lane & 31;
    const int half = lane >> 5;

    // per-n pixel base into padded x (b folded in; LPX%64==0 so b-uniform)
    unsigned pbase[2];
#pragma unroll
    for (int n = 0; n < 2; ++n) {
        int gp = pt0 + n * 32 + lm;
        int br = gp / LPX;
        int pr = gp - br * LPX;
        int ypx = pr / WW;
        int xpx = pr - ypx * WW;
        pbase[n] = (unsigned)(br * (CIN * PPL) + ypx * PW + xpx);
    }

    const uint4* wAh = (const uint4*)Wph + w * 128 + lane;
    const uint4* wAl = (const uint4*)Wpl + w * 128 + lane;

    float16v acc[2];
#pragma unroll
    for (int n = 0; n < 2; ++n)
#pragma unroll
        for (int i = 0; i < 16; ++i) acc[n][i] = 0.f;

    // B-word ping-pong buffers at (step,n) granularity: g = it*2 + n.
    // Words for g+1 are issued at the top of g -> one full iteration
    // (~6 MFMAs + perms) of latency cover. All indices compile-time.
    unsigned wb[2][16];
    uint4 Ah[2], Al[2];

#define LOADB(G, BUF)                                                          \
    {                                                                          \
        const int it_ = (G) >> 1, n_ = (G) & 1;                                \
        _Pragma("unroll") for (int s = 0; s < 2; ++s)                          \
        _Pragma("unroll") for (int j = 0; j < 8; ++j) {                        \
            const unsigned o0 = DOFF(it_ * 32 + s * 16 + j);                   \
            const unsigned o1 = DOFF(it_ * 32 + s * 16 + 8 + j);               \
            wb[BUF][s * 8 + j] = xpad[pbase[n_] + (half ? o1 : o0)];           \
        }                                                                      \
    }

    LOADB(0, 0)

#pragma unroll
    for (int g = 0; g < 36; ++g) {
        const int it = g >> 1;
        const int n  = g & 1;

        // A loads for this K-step (L2-hot; issued before perms so the VALU
        // repack + other waves cover the latency)
        if (n == 0) {
#pragma unroll
            for (int s = 0; s < 2; ++s) {
                Ah[s] = wAh[it * 512 + s * 64];
                Al[s] = wAl[it * 512 + s * 64];
            }
        }

        // issue next (step,n)'s B gathers into the other buffer
        if (g < 35) { LOADB(g + 1, ((g + 1) & 1)) }

        // repack current words -> fragments (identical values to R5's LDS
        // route: Bh word m = hi(d_2m)|hi(d_2m+1)<<16, Bl = lo pair)
        short8 Bh[2], Bl[2];
#pragma unroll
        for (int s = 0; s < 2; ++s)
#pragma unroll
            for (int m = 0; m < 4; ++m) {
                ((unsigned*)&Bh[s])[m] = __builtin_amdgcn_perm(
                    wb[g & 1][s * 8 + 2 * m + 1], wb[g & 1][s * 8 + 2 * m],
                    0x05040100u);
                ((unsigned*)&Bl[s])[m] = __builtin_amdgcn_perm(
                    wb[g & 1][s * 8 + 2 * m + 1], wb[g & 1][s * 8 + 2 * m],
                    0x07060302u);
            }

        // 6 MFMAs into acc[n] — order identical to R5
        acc[n] = __builtin_amdgcn_mfma_f32_32x32x16_bf16(
            *(const short8*)&Ah[0], Bh[0], acc[n], 0, 0, 0);
        acc[n] = __builtin_amdgcn_mfma_f32_32x32x16_bf16(
            *(const short8*)&Ah[0], Bl[0], acc[n], 0, 0, 0);
        acc[n] = __builtin_amdgcn_mfma_f32_32x32x16_bf16(
            *(const short8*)&Al[0], Bh[0], acc[n], 0, 0, 0);
        acc[n] = __builtin_amdgcn_mfma_f32_32x32x16_bf16(
            *(const short8*)&Ah[1], Bh[1], acc[n], 0, 0, 0);
        acc[n] = __builtin_amdgcn_mfma_f32_32x32x16_bf16(
            *(const short8*)&Ah[1], Bl[1], acc[n], 0, 0, 0);
        acc[n] = __builtin_amdgcn_mfma_f32_32x32x16_bf16(
            *(const short8*)&Al[1], Bh[1], acc[n], 0, 0, 0);
    }
#undef LOADB

#pragma unroll
    for (int n = 0; n < 2; ++n) {
        const int gp0 = pt0 + n * 32;
        const int bpos = gp0 / LPX;
        const int pxb = gp0 - bpos * LPX + lm;
        const size_t outb = (size_t)bpos * COUT * LPX;
#pragma unroll
        for (int reg = 0; reg < 16; ++reg) {
            int o = w * 32 + 4 * half + (reg & 3) + 8 * (reg >> 2);
            float z = acc[n][reg] + bias[o];
            float q = rintf(__fmul_rn(z, 0.63661975f));
            float rr = fmaf(q, -1.5707964f, z);
            float d = fabsf(fabsf(rr) - 0.78539816f);
            size_t oidx = outb + (size_t)o * LPX + pxb;
            out[oidx] = (float)(((int)q) & 1);
            if (d < MARGIN) {
                unsigned pos = atomicAdd(wcount, 1u);
                if (pos < wcap) wlist[pos] = (unsigned)oidx;
            }
        }
    }
}

// ---- wave-cooperative fixup: 1 wave per 4 elements. Lanes gather (parallel,
// BW-bound); lanes 0-3 run the bit-exact kc=384-split serial FMA chain from
// LDS (order identical to R9 -> bit-identical z). ----
__global__ __launch_bounds__(64)
void exact_fix_wave(const float* __restrict__ x,
                    const float* __restrict__ Wt,
                    const float* __restrict__ bias,
                    float* __restrict__ out,
                    const unsigned* __restrict__ wcount,
                    const unsigned* __restrict__ wlist,
                    unsigned wcap) {
#pragma clang fp contract(off)
    __shared__ float sx[4][DD];
    __shared__ float sw[4][DD];
    const int lane = threadIdx.x;        // block = 1 wave
    unsigned n = *wcount;
    if (n > wcap) n = wcap;

    for (unsigned e0 = blockIdx.x * 4; e0 < n; e0 += gridDim.x * 4) {
        // gather 4 elements: lane = channel c
        unsigned idxs[4];
#pragma unroll
        for (int j = 0; j < 4; ++j) {
            unsigned e = e0 + j;
            if (e >= n) { idxs[j] = 0xFFFFFFFFu; continue; }
            unsigned idx = wlist[e];
            idxs[j] = idx;
            int px = idx % WW;
            unsigned t = idx / WW;
            int py = t % HH;  t /= HH;
            int o  = t % COUT;
            int b  = t / COUT;
            const float* xc = x  + ((size_t)(b * CIN + lane)) * LPX;
            const float* wc = Wt + (size_t)o * DD + lane * 9;
#pragma unroll
            for (int u = 0; u < 3; ++u)
#pragma unroll
                for (int v = 0; v < 3; ++v) {
                    int tp = u * 3 + v;
                    int gy = py + u - 1, gx = px + v - 1;
                    float p = ((unsigned)gy < HH && (unsigned)gx < WW)
                                  ? xc[gy * WW + gx] : 0.f;
                    sx[j][lane * 9 + tp] = p;
                    sw[j][lane * 9 + tp] = wc[tp];
                }
        }
        __syncthreads();
        if (lane < 4 && idxs[lane] != 0xFFFFFFFFu) {
            const float* px_ = sx[lane];
            const float* pw_ = sw[lane];
            float accA = 0.f, accB2 = 0.f;
            for (int d = 0; d < KC; ++d)        accA  = fmaf(px_[d], pw_[d], accA);
            for (int d = KC; d < DD; ++d)       accB2 = fmaf(px_[d], pw_[d], accB2);
            unsigned idx = idxs[lane];
            int o = (idx / LPX) % COUT;
            float zG = __fadd_rn(accA, accB2);
            float z  = __fadd_rn(zG, bias[o]);
            out[idx] = (float)dec_np(z);
        }
        __syncthreads();
    }
}

// ---- fallback (verified R9 path) ----
__global__ __launch_bounds__(256)
void np_emul_conv(const float* __restrict__ x,
                  const float* __restrict__ Wt,
                  const float* __restrict__ bias,
                  float* __restrict__ out) {
#pragma clang fp contract(off)
    int idx = blockIdx.x * 256 + threadIdx.x;
    if (idx >= TOTAL) return;
    int px = idx % WW;
    int t  = idx / WW;
    int py = t % HH;  t /= HH;
    int o  = t % COUT;
    int b  = t / COUT;
    const float* wrow = Wt + (size_t)o * DD;
    const float* xb   = x + (size_t)b * CIN * LPX;
    float accA = 0.f, accB2 = 0.f;
    for (int c = 0; c < CIN; ++c) {
        const float* xc = xb + c * LPX;
        const float* wc = wrow + c * 9;
        int dbase = c * 9;
#pragma unroll
        for (int u = 0; u < 3; ++u)
#pragma unroll
            for (int v = 0; v < 3; ++v) {
                int tp = u * 3 + v;
                int gy = py + u - 1, gx = px + v - 1;
                float p = ((unsigned)gy < HH && (unsigned)gx < WW) ? xc[gy * WW + gx] : 0.f;
                if (dbase + tp < KC) accA  = fmaf(p, wc[tp], accA);
                else                 accB2 = fmaf(p, wc[tp], accB2);
            }
    }
    float z = __fadd_rn(__fadd_rn(accA, accB2), bias[o]);
    out[idx] = (float)dec_np(z);
}

extern "C" void kernel_launch(void* const* d_in, const int* in_sizes, int n_in,
                              void* d_out, int out_size, void* d_ws, size_t ws_size,
                              hipStream_t stream) {
    const float* x  = (const float*)d_in[0];
    const float* Wt = (const float*)d_in[1];
    const float* bb = (const float*)d_in[2];
    float* out = (float*)d_out;

    const size_t WSPLIT = (size_t)COUT * DD * 2;          // 147456 B each
    const size_t XP     = (size_t)NXP * 4;                // 27.56 MB padded
    const size_t FIXED  = 2 * WSPLIT + XP + 4;

    if (ws_size >= FIXED + 65536) {
        unsigned short* Wph = (unsigned short*)d_ws;
        unsigned short* Wpl = Wph + COUT * DD;
        unsigned* xpad   = (unsigned*)((char*)d_ws + 2 * WSPLIT);
        unsigned* wcount = (unsigned*)((char*)d_ws + 2 * WSPLIT + XP);
        unsigned* wlist  = wcount + 1;
        size_t avail = (ws_size - FIXED) / 4;
        unsigned wcap = (avail > 2000000u) ? 2000000u : (unsigned)avail;

        prep_all<<<dim3(NXP / 256), dim3(256), 0, stream>>>(x, Wt, xpad, Wph, Wpl, wcount);
        conv_mfma<<<dim3(1568), dim3(256), 0, stream>>>(xpad, Wph, Wpl, bb, out,
                                                        wcount, wlist, wcap);
        exact_fix_wave<<<dim3(1024), dim3(64), 0, stream>>>(x, Wt, bb, out,
                                                            wcount, wlist, wcap);
    } else {
        np_emul_conv<<<(TOTAL + 255) / 256, 256, 0, stream>>>(x, Wt, bb, out);
    }
}

// Round 7
// 238.599 us; speedup vs baseline: 7.4110x; 7.4110x over previous
//
#include <hip/hip_runtime.h>
#include <math.h>

// B=32, Cin=64, H=W=56, Cout=128, K=3 pad=1 -> D=576, out (32,128,56,56) fp32
#define B_    32
#define CIN   64
#define HH    56
#define WW    56
#define COUT  128
#define DD    576
#define KC    384            // OpenBLAS kc split (verified R9)
#define LPX   (HH*WW)        // 3136 = 49*64
#define TOTAL (B_*COUT*LPX)
#define NX    (B_*CIN*LPX)   // 6422528
#define PW    58             // padded plane width/height
#define PPL   (PW*PW)        // 3364 words per padded channel plane
#define NXP   (B_*CIN*PPL)   // 6889472 words
#define MARGIN 4e-4f         // worst-case split-bf16 + reorder bound (validated R15-18)

typedef __attribute__((ext_vector_type(8)))  short  short8;
typedef __attribute__((ext_vector_type(16))) float  float16v;

__device__ __forceinline__ unsigned short bf16_rne(float f) {
    unsigned u = __float_as_uint(f);
    unsigned r = u + 0x7FFFu + ((u >> 16) & 1u);
    return (unsigned short)(r >> 16);
}
__device__ __forceinline__ float bf16_to_f(unsigned short h) {
    return __uint_as_float(((unsigned)h) << 16);
}

// ---- bit-exact numpy FLOAT_sin (npyv FMA path) — verified R9 ----
__device__ __forceinline__ float np_sinf(float x) {
#pragma clang fp contract(off)
    const float rint_cvt = 0x1.8p+23f;
    float q = __fmul_rn(x, 0x1.45f306p-1f);
    q = __fadd_rn(q, rint_cvt);
    q = __fsub_rn(q, rint_cvt);
    float r = fmaf(q, -0x1.921fb0p+0f, x);
    r = fmaf(q, -0x1.5110b4p-22f, r);
    r = fmaf(q, -0x1.846988p-48f, r);
    float r2 = __fmul_rn(r, r);
    float s = fmaf(0x1.7d3bbcp-19f, r2, -0x1.a06bbap-13f);
    s = fmaf(s, r2, 0x1.11119ap-7f);
    s = fmaf(s, r2, -0x1.555556p-3f);
    s = __fmul_rn(s, r2);
    s = fmaf(s, r, r);
    float c = fmaf(0x1.98e616p-16f, r2, -0x1.6c06dcp-10f);
    c = fmaf(c, r2, 0x1.55553cp-5f);
    c = fmaf(c, r2, -0.5f);
    c = fmaf(c, r2, 1.0f);
    int iq = (int)q;
    float res = (iq & 1) ? c : s;
    unsigned sgn = ((unsigned)(iq & 2)) << 30;
    return __uint_as_float(__float_as_uint(res) ^ sgn);
}
__device__ __forceinline__ int dec_np(float z) {
    float s = np_sinf(z);
    return (__fmul_rn(s, s) > 0.5f) ? 1 : 0;
}

// ---- merged prep: W -> fragment-major bf16 hi/lo pack, x -> padded 58x58
// planes of (hi | lo<<16) u32 words, borders zero (verified R3/R4/R5) ----
// W dst for (o,k): k18=k/32, kr=k%32, s=kr/16, half=(kr%16)/8, j=kr%8
//   lane = half*32 + (o%32), ot = o/32
//   idx  = (((k18*4 + ot)*2 + s)*64 + lane)*8 + j
__global__ __launch_bounds__(256)
void prep_all(const float* __restrict__ x, const float* __restrict__ W,
              unsigned* __restrict__ xpad,
              unsigned short* __restrict__ Wph, unsigned short* __restrict__ Wpl,
              unsigned* __restrict__ wcount) {
    int i = blockIdx.x * 256 + threadIdx.x;
    if (i == 0) *wcount = 0;
    if (i < COUT * DD) {
        int o = i / DD, k = i - o * DD;
        float w = W[i];
        unsigned short h = bf16_rne(w);
        unsigned short l = bf16_rne(w - bf16_to_f(h));
        int k18 = k >> 5, kr = k & 31;
        int s = (kr >> 4) & 1, half = (kr >> 3) & 1, j = kr & 7;
        int lane = half * 32 + (o & 31);
        int ot = o >> 5;
        unsigned dst = ((((unsigned)(k18 * 4 + ot)) * 2 + s) * 64 + lane) * 8 + j;
        Wph[dst] = h;
        Wpl[dst] = l;
    }
    if (i < NXP) {
        int bc = i / PPL;
        int r  = i - bc * PPL;
        int yy = r / PW;
        int xx = r - yy * PW;
        unsigned v = 0u;
        if (yy >= 1 && yy <= HH && xx >= 1 && xx <= WW) {
            float f = x[(size_t)bc * LPX + (yy - 1) * WW + (xx - 1)];
            unsigned short h = bf16_rne(f);
            unsigned short l = bf16_rne(f - bf16_to_f(h));
            v = (unsigned)h | ((unsigned)l << 16);
        }
        xpad[i] = v;
    }
}

// ---- MFMA conv: barrier-free, LDS-free (R6 structure), with ALL register
// indexing compile-time (named ping-pong wbA/wbB, named acc0/acc1, literal
// STEP(IT) expansion -> SROA promotes to registers; fixes R6's scratch
// demotion that caused 6.9GB of spill traffic). Arithmetic & MFMA order
// identical to R5/R6 (R6 passed absmax=0) -> MARGIN still valid.
#define DOFF(d) ((unsigned)((((d) / 9) * PPL) + ((((d) % 9) / 3) * PW) + (((d) % 9) % 3)))

__global__ __launch_bounds__(256, 4)
void conv_mfma(const unsigned* __restrict__ xpad,
               const unsigned short* __restrict__ Wph,
               const unsigned short* __restrict__ Wpl,
               const float* __restrict__ bias,
               float* __restrict__ out,
               unsigned* __restrict__ wcount,
               unsigned* __restrict__ wlist,
               unsigned wcap) {
    const int tid = threadIdx.x;
    // XCD-chunked bijective swizzle (1568 = 8*196): per-XCD contiguous chunk
    // = exactly 4 batches of xpad (~3.4MB -> fits 4MB L2).
    const int bid = (blockIdx.x & 7) * 196 + (blockIdx.x >> 3);
    const int pt0 = bid * 64;            // 64-px tile, never crosses a batch

    const int w    = tid >> 6;           // o-tile (0..3)
    const int lane = tid & 63;
    const int lm   = lane & 31;
    const int half = lane >> 5;

    // per-n pixel base into padded x (b folded in; LPX%64==0 so b-uniform)
    unsigned pbase0, pbase1;
    {
        int gp = pt0 + lm;
        int br = gp / LPX;
        int pr = gp - br * LPX;
        int ypx = pr / WW;
        int xpx = pr - ypx * WW;
        pbase0 = (unsigned)(br * (CIN * PPL) + ypx * PW + xpx);
        gp = pt0 + 32 + lm;
        br = gp / LPX;
        pr = gp - br * LPX;
        ypx = pr / WW;
        xpx = pr - ypx * WW;
        pbase1 = (unsigned)(br * (CIN * PPL) + ypx * PW + xpx);
    }

    const uint4* wAh = (const uint4*)Wph + w * 128 + lane;
    const uint4* wAl = (const uint4*)Wpl + w * 128 + lane;

    float16v acc0, acc1;
#pragma unroll
    for (int i = 0; i < 16; ++i) { acc0[i] = 0.f; acc1[i] = 0.f; }

    // named ping-pong B-word buffers; ALL accesses literal-indexed
    unsigned wbA[16], wbB[16];
    uint4 Ah0, Ah1, Al0, Al1;

#define GATHER(IT, PB, BUF)                                                    \
    {                                                                          \
        _Pragma("unroll") for (int s = 0; s < 2; ++s)                          \
        _Pragma("unroll") for (int j = 0; j < 8; ++j) {                        \
            const unsigned o0 = DOFF((IT) * 32 + s * 16 + j);                  \
            const unsigned o1 = DOFF((IT) * 32 + s * 16 + 8 + j);              \
            BUF[s * 8 + j] = xpad[PB + (half ? o1 : o0)];                      \
        }                                                                      \
    }

#define LOADA(IT)                                                              \
    Ah0 = wAh[(IT) * 512];      Ah1 = wAh[(IT) * 512 + 64];                    \
    Al0 = wAl[(IT) * 512];      Al1 = wAl[(IT) * 512 + 64];

    // perm repack + 6 MFMAs, order identical to R5 (verified bit-exact)
#define PERMM(BUF, ACC)                                                        \
    {                                                                          \
        short8 Bh0, Bl0, Bh1, Bl1;                                             \
        _Pragma("unroll") for (int m = 0; m < 4; ++m) {                        \
            ((unsigned*)&Bh0)[m] = __builtin_amdgcn_perm(                      \
                BUF[2 * m + 1], BUF[2 * m], 0x05040100u);                      \
            ((unsigned*)&Bl0)[m] = __builtin_amdgcn_perm(                      \
                BUF[2 * m + 1], BUF[2 * m], 0x07060302u);                      \
            ((unsigned*)&Bh1)[m] = __builtin_amdgcn_perm(                      \
                BUF[8 + 2 * m + 1], BUF[8 + 2 * m], 0x05040100u);              \
            ((unsigned*)&Bl1)[m] = __builtin_amdgcn_perm(                      \
                BUF[8 + 2 * m + 1], BUF[8 + 2 * m], 0x07060302u);              \
        }                                                                      \
        ACC = __builtin_amdgcn_mfma_f32_32x32x16_bf16(                         \
            *(const short8*)&Ah0, Bh0, ACC, 0, 0, 0);                          \
        ACC = __builtin_amdgcn_mfma_f32_32x32x16_bf16(                         \
            *(const short8*)&Ah0, Bl0, ACC, 0, 0, 0);                          \
        ACC = __builtin_amdgcn_mfma_f32_32x32x16_bf16(                         \
            *(const short8*)&Al0, Bh0, ACC, 0, 0, 0);                          \
        ACC = __builtin_amdgcn_mfma_f32_32x32x16_bf16(                         \
            *(const short8*)&Ah1, Bh1, ACC, 0, 0, 0);                          \
        ACC = __builtin_amdgcn_mfma_f32_32x32x16_bf16(                         \
            *(const short8*)&Ah1, Bl1, ACC, 0, 0, 0);                          \
        ACC = __builtin_amdgcn_mfma_f32_32x32x16_bf16(                         \
            *(const short8*)&Al1, Bh1, ACC, 0, 0, 0);                          \
    }

    // steady-state step: consume wbA (IT,n=0) and wbB (IT,n=1), prefetch
    // each gather one half-step ahead under the other half's MFMAs
#define STEP(IT)                                                               \
    LOADA(IT)                                                                  \
    GATHER(IT, pbase1, wbB)                                                    \
    PERMM(wbA, acc0)                                                           \
    GATHER((IT) + 1, pbase0, wbA)                                              \
    PERMM(wbB, acc1)

    GATHER(0, pbase0, wbA)
    STEP(0)  STEP(1)  STEP(2)  STEP(3)  STEP(4)  STEP(5)
    STEP(6)  STEP(7)  STEP(8)  STEP(9)  STEP(10) STEP(11)
    STEP(12) STEP(13) STEP(14) STEP(15) STEP(16)
    // last step: no (IT+1) prefetch
    LOADA(17)
    GATHER(17, pbase1, wbB)
    PERMM(wbA, acc0)
    PERMM(wbB, acc1)

#undef GATHER
#undef LOADA
#undef PERMM
#undef STEP

#define EPI(N, ACC)                                                            \
    {                                                                          \
        const int gp0 = pt0 + (N) * 32;                                        \
        const int bpos = gp0 / LPX;                                            \
        const int pxb = gp0 - bpos * LPX + lm;                                 \
        const size_t outb = (size_t)bpos * COUT * LPX;                         \
        _Pragma("unroll") for (int reg = 0; reg < 16; ++reg) {                 \
            int o = w * 32 + 4 * half + (reg & 3) + 8 * (reg >> 2);            \
            float z = ACC[reg] + bias[o];                                      \
            float q = rintf(__fmul_rn(z, 0.63661975f));                        \
            float rr = fmaf(q, -1.5707964f, z);                                \
            float d = fabsf(fabsf(rr) - 0.78539816f);                          \
            size_t oidx = outb + (size_t)o * LPX + pxb;                        \
            out[oidx] = (float)(((int)q) & 1);                                 \
            if (d < MARGIN) {                                                  \
                unsigned pos = atomicAdd(wcount, 1u);                          \
                if (pos < wcap) wlist[pos] = (unsigned)oidx;                   \
            }                                                                  \
        }                                                                      \
    }

    EPI(0, acc0)
    EPI(1, acc1)
#undef EPI
}

// ---- wave-cooperative fixup: 1 wave per 4 elements. Lanes gather (parallel,
// BW-bound); lanes 0-3 run the bit-exact kc=384-split serial FMA chain from
// LDS (order identical to R9 -> bit-identical z). ----
__global__ __launch_bounds__(64)
void exact_fix_wave(const float* __restrict__ x,
                    const float* __restrict__ Wt,
                    const float* __restrict__ bias,
                    float* __restrict__ out,
                    const unsigned* __restrict__ wcount,
                    const unsigned* __restrict__ wlist,
                    unsigned wcap) {
#pragma clang fp contract(off)
    __shared__ float sx[4][DD];
    __shared__ float sw[4][DD];
    const int lane = threadIdx.x;        // block = 1 wave
    unsigned n = *wcount;
    if (n > wcap) n = wcap;

    for (unsigned e0 = blockIdx.x * 4; e0 < n; e0 += gridDim.x * 4) {
        // gather 4 elements: lane = channel c
        unsigned idxs[4];
#pragma unroll
        for (int j = 0; j < 4; ++j) {
            unsigned e = e0 + j;
            if (e >= n) { idxs[j] = 0xFFFFFFFFu; continue; }
            unsigned idx = wlist[e];
            idxs[j] = idx;
            int px = idx % WW;
            unsigned t = idx / WW;
            int py = t % HH;  t /= HH;
            int o  = t % COUT;
            int b  = t / COUT;
            const float* xc = x  + ((size_t)(b * CIN + lane)) * LPX;
            const float* wc = Wt + (size_t)o * DD + lane * 9;
#pragma unroll
            for (int u = 0; u < 3; ++u)
#pragma unroll
                for (int v = 0; v < 3; ++v) {
                    int tp = u * 3 + v;
                    int gy = py + u - 1, gx = px + v - 1;
                    float p = ((unsigned)gy < HH && (unsigned)gx < WW)
                                  ? xc[gy * WW + gx] : 0.f;
                    sx[j][lane * 9 + tp] = p;
                    sw[j][lane * 9 + tp] = wc[tp];
                }
        }
        __syncthreads();
        if (lane < 4 && idxs[lane] != 0xFFFFFFFFu) {
            const float* px_ = sx[lane];
            const float* pw_ = sw[lane];
            float accA = 0.f, accB2 = 0.f;
            for (int d = 0; d < KC; ++d)        accA  = fmaf(px_[d], pw_[d], accA);
            for (int d = KC; d < DD; ++d)       accB2 = fmaf(px_[d], pw_[d], accB2);
            unsigned idx = idxs[lane];
            int o = (idx / LPX) % COUT;
            float zG = __fadd_rn(accA, accB2);
            float z  = __fadd_rn(zG, bias[o]);
            out[idx] = (float)dec_np(z);
        }
        __syncthreads();
    }
}

// ---- fallback (verified R9 path) ----
__global__ __launch_bounds__(256)
void np_emul_conv(const float* __restrict__ x,
                  const float* __restrict__ Wt,
                  const float* __restrict__ bias,
                  float* __restrict__ out) {
#pragma clang fp contract(off)
    int idx = blockIdx.x * 256 + threadIdx.x;
    if (idx >= TOTAL) return;
    int px = idx % WW;
    int t  = idx / WW;
    int py = t % HH;  t /= HH;
    int o  = t % COUT;
    int b  = t / COUT;
    const float* wrow = Wt + (size_t)o * DD;
    const float* xb   = x + (size_t)b * CIN * LPX;
    float accA = 0.f, accB2 = 0.f;
    for (int c = 0; c < CIN; ++c) {
        const float* xc = xb + c * LPX;
        const float* wc = wrow + c * 9;
        int dbase = c * 9;
#pragma unroll
        for (int u = 0; u < 3; ++u)
#pragma unroll
            for (int v = 0; v < 3; ++v) {
                int tp = u * 3 + v;
                int gy = py + u - 1, gx = px + v - 1;
                float p = ((unsigned)gy < HH && (unsigned)gx < WW) ? xc[gy * WW + gx] : 0.f;
                if (dbase + tp < KC) accA  = fmaf(p, wc[tp], accA);
                else                 accB2 = fmaf(p, wc[tp], accB2);
            }
    }
    float z = __fadd_rn(__fadd_rn(accA, accB2), bias[o]);
    out[idx] = (float)dec_np(z);
}

extern "C" void kernel_launch(void* const* d_in, const int* in_sizes, int n_in,
                              void* d_out, int out_size, void* d_ws, size_t ws_size,
                              hipStream_t stream) {
    const float* x  = (const float*)d_in[0];
    const float* Wt = (const float*)d_in[1];
    const float* bb = (const float*)d_in[2];
    float* out = (float*)d_out;

    const size_t WSPLIT = (size_t)COUT * DD * 2;          // 147456 B each
    const size_t XP     = (size_t)NXP * 4;                // 27.56 MB padded
    const size_t FIXED  = 2 * WSPLIT + XP + 4;

    if (ws_size >= FIXED + 65536) {
        unsigned short* Wph = (unsigned short*)d_ws;
        unsigned short* Wpl = Wph + COUT * DD;
        unsigned* xpad   = (unsigned*)((char*)d_ws + 2 * WSPLIT);
        unsigned* wcount = (unsigned*)((char*)d_ws + 2 * WSPLIT + XP);
        unsigned* wlist  = wcount + 1;
        size_t avail = (ws_size - FIXED) / 4;
        unsigned wcap = (avail > 2000000u) ? 2000000u : (unsigned)avail;

        prep_all<<<dim3(NXP / 256), dim3(256), 0, stream>>>(x, Wt, xpad, Wph, Wpl, wcount);
        conv_mfma<<<dim3(1568), dim3(256), 0, stream>>>(xpad, Wph, Wpl, bb, out,
                                                        wcount, wlist, wcap);
        exact_fix_wave<<<dim3(1024), dim3(64), 0, stream>>>(x, Wt, bb, out,
                                                            wcount, wlist, wcap);
    } else {
        np_emul_conv<<<(TOTAL + 255) / 256, 256, 0, stream>>>(x, Wt, bb, out);
    }
}

// Round 8
// 229.670 us; speedup vs baseline: 7.6991x; 1.0389x over previous
//
#include <hip/hip_runtime.h>
#include <math.h>

// B=32, Cin=64, H=W=56, Cout=128, K=3 pad=1 -> D=576, out (32,128,56,56) fp32
#define B_    32
#define CIN   64
#define HH    56
#define WW    56
#define COUT  128
#define DD    576
#define KC    384            // OpenBLAS kc split (verified R9)
#define LPX   (HH*WW)        // 3136 = 49*64
#define TOTAL (B_*COUT*LPX)
#define NX    (B_*CIN*LPX)   // 6422528
#define PW    58             // padded plane width/height
#define PPL   (PW*PW)        // 3364 words per padded channel plane
#define NXP   (B_*CIN*PPL)   // 6889472 words
#define MARGIN 4e-4f         // worst-case split-bf16 + reorder bound (validated R15-18)

typedef __attribute__((ext_vector_type(8)))  short  short8;
typedef __attribute__((ext_vector_type(16))) float  float16v;

__device__ __forceinline__ unsigned short bf16_rne(float f) {
    unsigned u = __float_as_uint(f);
    unsigned r = u + 0x7FFFu + ((u >> 16) & 1u);
    return (unsigned short)(r >> 16);
}
__device__ __forceinline__ float bf16_to_f(unsigned short h) {
    return __uint_as_float(((unsigned)h) << 16);
}

// async global->LDS staging: wave-uniform LDS base (lane l writes word l),
// per-lane global source. Tracked by vmcnt.
__device__ __forceinline__ void gload_lds4(const unsigned* g, unsigned* l) {
    __builtin_amdgcn_global_load_lds(
        (const __attribute__((address_space(1))) unsigned*)g,
        (__attribute__((address_space(3))) unsigned*)l, 4, 0, 0);
}

// ---- bit-exact numpy FLOAT_sin (npyv FMA path) — verified R9 ----
__device__ __forceinline__ float np_sinf(float x) {
#pragma clang fp contract(off)
    const float rint_cvt = 0x1.8p+23f;
    float q = __fmul_rn(x, 0x1.45f306p-1f);
    q = __fadd_rn(q, rint_cvt);
    q = __fsub_rn(q, rint_cvt);
    float r = fmaf(q, -0x1.921fb0p+0f, x);
    r = fmaf(q, -0x1.5110b4p-22f, r);
    r = fmaf(q, -0x1.846988p-48f, r);
    float r2 = __fmul_rn(r, r);
    float s = fmaf(0x1.7d3bbcp-19f, r2, -0x1.a06bbap-13f);
    s = fmaf(s, r2, 0x1.11119ap-7f);
    s = fmaf(s, r2, -0x1.555556p-3f);
    s = __fmul_rn(s, r2);
    s = fmaf(s, r, r);
    float c = fmaf(0x1.98e616p-16f, r2, -0x1.6c06dcp-10f);
    c = fmaf(c, r2, 0x1.55553cp-5f);
    c = fmaf(c, r2, -0.5f);
    c = fmaf(c, r2, 1.0f);
    int iq = (int)q;
    float res = (iq & 1) ? c : s;
    unsigned sgn = ((unsigned)(iq & 2)) << 30;
    return __uint_as_float(__float_as_uint(res) ^ sgn);
}
__device__ __forceinline__ int dec_np(float z) {
    float s = np_sinf(z);
    return (__fmul_rn(s, s) > 0.5f) ? 1 : 0;
}

// ---- merged prep (x4 vectorized): W -> fragment-major bf16 hi/lo pack,
// x -> padded 58x58 planes of (hi | lo<<16) u32 words, borders zero ----
// W dst for (o,k): k18=k/32, kr=k%32, s=kr/16, half=(kr%16)/8, j=kr%8
//   lane = half*32 + (o%32), ot = o/32
//   idx  = (((k18*4 + ot)*2 + s)*64 + lane)*8 + j
__global__ __launch_bounds__(256)
void prep_all(const float* __restrict__ x, const float* __restrict__ W,
              unsigned* __restrict__ xpad,
              unsigned short* __restrict__ Wph, unsigned short* __restrict__ Wpl,
              unsigned* __restrict__ wcount) {
    int i4 = (blockIdx.x * 256 + threadIdx.x) * 4;
    if (i4 == 0) *wcount = 0;
    if (i4 < COUT * DD) {               // COUT*DD % 4 == 0
#pragma unroll
        for (int e = 0; e < 4; ++e) {
            int i = i4 + e;
            int o = i / DD, k = i - o * DD;
            float w = W[i];
            unsigned short h = bf16_rne(w);
            unsigned short l = bf16_rne(w - bf16_to_f(h));
            int k18 = k >> 5, kr = k & 31;
            int s = (kr >> 4) & 1, half = (kr >> 3) & 1, j = kr & 7;
            int lane = half * 32 + (o & 31);
            int ot = o >> 5;
            unsigned dst = ((((unsigned)(k18 * 4 + ot)) * 2 + s) * 64 + lane) * 8 + j;
            Wph[dst] = h;
            Wpl[dst] = l;
        }
    }
    if (i4 < NXP) {                      // NXP % 4 == 0
        unsigned vv[4];
#pragma unroll
        for (int e = 0; e < 4; ++e) {
            int i = i4 + e;
            int bc = i / PPL;
            int r  = i - bc * PPL;
            int yy = r / PW;
            int xx = r - yy * PW;
            unsigned v = 0u;
            if (yy >= 1 && yy <= HH && xx >= 1 && xx <= WW) {
                float f = x[(size_t)bc * LPX + (yy - 1) * WW + (xx - 1)];
                unsigned short h = bf16_rne(f);
                unsigned short l = bf16_rne(f - bf16_to_f(h));
                v = (unsigned)h | ((unsigned)l << 16);
            }
            vv[e] = v;
        }
        *(uint4*)(xpad + i4) = *(uint4*)vv;
    }
}

// ---- MFMA conv: 64px x 128out, 4 waves. B staged ONCE per block via
// global_load_lds DMA into P[d][px] (no reg round trip, no publish VALU,
// no ds_writes); A direct global->reg (L2-hot, zero duplication); consumer
// ds_read (bank=lm, conflict-free) + v_perm repack (R7-verified values).
// One vmcnt(0)+barrier per step. All literal-indexed (rule #20).
// Per-acc MFMA order identical to R5/R7 -> bit-identical acc -> MARGIN valid.
#define DOFF(d) ((unsigned)((((d) / 9) * PPL) + ((((d) % 9) / 3) * PW) + (((d) % 9) % 3)))

__global__ __launch_bounds__(256, 4)
void conv_mfma(const unsigned* __restrict__ xpad,
               const unsigned short* __restrict__ Wph,
               const unsigned short* __restrict__ Wpl,
               const float* __restrict__ bias,
               float* __restrict__ out,
               unsigned* __restrict__ wcount,
               unsigned* __restrict__ wlist,
               unsigned wcap) {
    __shared__ __align__(16) unsigned Pb[2][32][64];   // 16KB dbuf

    const int tid = threadIdx.x;
    // XCD-chunked bijective swizzle (1568 = 8*196): per-XCD contiguous chunk
    // = exactly 4 batches of xpad (~3.4MB -> fits 4MB L2).
    const int bid = (blockIdx.x & 7) * 196 + (blockIdx.x >> 3);
    const int pt0 = bid * 64;            // 64-px tile, never crosses a batch

    const int w    = tid >> 6;           // o-tile (0..3)
    const int lane = tid & 63;
    const int lm   = lane & 31;
    const int half = lane >> 5;
    const int wrow = w * 512;            // this wave's 8 LDS d-rows (words)

    // DMA pixel base: lane l <-> pixel pt0+l (coalesced across the wave)
    const unsigned* xbl;
    {
        int gp = pt0 + lane;
        int br = gp / LPX;
        int pr = gp - br * LPX;
        int ypx = pr / WW;
        int xpx = pr - ypx * WW;
        xbl = xpad + (unsigned)(br * (CIN * PPL) + ypx * PW + xpx);
    }

    const uint4* wAh = (const uint4*)Wph + w * 128 + lane;
    const uint4* wAl = (const uint4*)Wpl + w * 128 + lane;

    float16v acc0, acc1;
#pragma unroll
    for (int i = 0; i < 16; ++i) { acc0[i] = 0.f; acc1[i] = 0.f; }

    uint4 AH0a, AH1a, AL0a, AL1a, AH0b, AH1b, AL0b, AL1b;

#define MFMA_(A, B, C) __builtin_amdgcn_mfma_f32_32x32x16_bf16(A, B, C, 0, 0, 0)

#define LOADA_(IT, H0, H1, L0, L1)                                             \
    H0 = wAh[(IT) * 512];      H1 = wAh[(IT) * 512 + 64];                      \
    L0 = wAl[(IT) * 512];      L1 = wAl[(IT) * 512 + 64];

    // wave w fills d-rows w*8+i (disjoint across waves); DOFF literal per w
#define DMA_(IT, BUF)                                                          \
    _Pragma("unroll") for (int i_ = 0; i_ < 8; ++i_) {                         \
        const unsigned o0_ = DOFF((IT) * 32 + i_);                             \
        const unsigned o1_ = DOFF((IT) * 32 + 8 + i_);                         \
        const unsigned o2_ = DOFF((IT) * 32 + 16 + i_);                        \
        const unsigned o3_ = DOFF((IT) * 32 + 24 + i_);                        \
        unsigned off_ = (w == 0) ? o0_ : (w == 1) ? o1_ : (w == 2) ? o2_ : o3_;\
        gload_lds4(xbl + off_, &Pb[BUF][0][0] + wrow + i_ * 64);               \
    }

    // consume one n-group: 16 LDS words -> perm -> 6 MFMAs (order == R5/R7)
#define CONS1_(BUF, N, H0, L0, H1, L1, ACC)                                    \
    {                                                                          \
        short8 Bh0, Bl0, Bh1, Bl1;                                             \
        _Pragma("unroll") for (int m_ = 0; m_ < 4; ++m_) {                     \
            unsigned a0 = Pb[BUF][half * 8 + 2 * m_    ][(N) * 32 + lm];       \
            unsigned a1 = Pb[BUF][half * 8 + 2 * m_ + 1][(N) * 32 + lm];       \
            unsigned b0 = Pb[BUF][16 + half * 8 + 2 * m_    ][(N) * 32 + lm];  \
            unsigned b1 = Pb[BUF][16 + half * 8 + 2 * m_ + 1][(N) * 32 + lm];  \
            ((unsigned*)&Bh0)[m_] = __builtin_amdgcn_perm(a1, a0, 0x05040100u);\
            ((unsigned*)&Bl0)[m_] = __builtin_amdgcn_perm(a1, a0, 0x07060302u);\
            ((unsigned*)&Bh1)[m_] = __builtin_amdgcn_perm(b1, b0, 0x05040100u);\
            ((unsigned*)&Bl1)[m_] = __builtin_amdgcn_perm(b1, b0, 0x07060302u);\
        }                                                                      \
        ACC = MFMA_(*(const short8*)&H0, Bh0, ACC);                            \
        ACC = MFMA_(*(const short8*)&H0, Bl0, ACC);                            \
        ACC = MFMA_(*(const short8*)&L0, Bh0, ACC);                            \
        ACC = MFMA_(*(const short8*)&H1, Bh1, ACC);                            \
        ACC = MFMA_(*(const short8*)&H1, Bl1, ACC);                            \
        ACC = MFMA_(*(const short8*)&L1, Bh1, ACC);                            \
    }

    // drain own DMAs (covered by the consume phase), rendezvous
#define SYNC_                                                                  \
    asm volatile("s_waitcnt vmcnt(0)" ::: "memory");                           \
    __builtin_amdgcn_s_barrier();                                              \
    asm volatile("" ::: "memory");

#define STEP_E(IT)                                                             \
    DMA_((IT) + 1, 1)                                                          \
    LOADA_((IT) + 1, AH0b, AH1b, AL0b, AL1b)                                   \
    CONS1_(0, 0, AH0a, AL0a, AH1a, AL1a, acc0)                                 \
    CONS1_(0, 1, AH0a, AL0a, AH1a, AL1a, acc1)                                 \
    SYNC_

#define STEP_O(IT)                                                             \
    DMA_((IT) + 1, 0)                                                          \
    LOADA_((IT) + 1, AH0a, AH1a, AL0a, AL1a)                                   \
    CONS1_(1, 0, AH0b, AL0b, AH1b, AL1b, acc0)                                 \
    CONS1_(1, 1, AH0b, AL0b, AH1b, AL1b, acc1)                                 \
    SYNC_

    // prologue: stage step 0, load A(0)
    LOADA_(0, AH0a, AH1a, AL0a, AL1a)
    DMA_(0, 0)
    SYNC_

    STEP_E(0)  STEP_O(1)  STEP_E(2)  STEP_O(3)  STEP_E(4)  STEP_O(5)
    STEP_E(6)  STEP_O(7)  STEP_E(8)  STEP_O(9)  STEP_E(10) STEP_O(11)
    STEP_E(12) STEP_O(13) STEP_E(14) STEP_O(15) STEP_E(16)
    // final step 17 (odd): consume buf1 / regset b, no prefetch, no sync
    CONS1_(1, 0, AH0b, AL0b, AH1b, AL1b, acc0)
    CONS1_(1, 1, AH0b, AL0b, AH1b, AL1b, acc1)

#undef STEP_E
#undef STEP_O
#undef SYNC_
#undef CONS1_
#undef DMA_
#undef LOADA_
#undef MFMA_

#define EPI(N, ACC)                                                            \
    {                                                                          \
        const int gp0 = pt0 + (N) * 32;                                        \
        const int bpos = gp0 / LPX;                                            \
        const int pxb = gp0 - bpos * LPX + lm;                                 \
        const size_t outb = (size_t)bpos * COUT * LPX;                         \
        _Pragma("unroll") for (int reg = 0; reg < 16; ++reg) {                 \
            int o = w * 32 + 4 * half + (reg & 3) + 8 * (reg >> 2);            \
            float z = ACC[reg] + bias[o];                                      \
            float q = rintf(__fmul_rn(z, 0.63661975f));                        \
            float rr = fmaf(q, -1.5707964f, z);                                \
            float d = fabsf(fabsf(rr) - 0.78539816f);                          \
            size_t oidx = outb + (size_t)o * LPX + pxb;                        \
            out[oidx] = (float)(((int)q) & 1);                                 \
            if (d < MARGIN) {                                                  \
                unsigned pos = atomicAdd(wcount, 1u);                          \
                if (pos < wcap) wlist[pos] = (unsigned)oidx;                   \
            }                                                                  \
        }                                                                      \
    }

    EPI(0, acc0)
    EPI(1, acc1)
#undef EPI
}

// ---- wave-cooperative fixup: 1 wave per 4 elements. Lanes gather (parallel,
// BW-bound); lanes 0-3 run the bit-exact kc=384-split serial FMA chain from
// LDS (order identical to R9 -> bit-identical z). ----
__global__ __launch_bounds__(64)
void exact_fix_wave(const float* __restrict__ x,
                    const float* __restrict__ Wt,
                    const float* __restrict__ bias,
                    float* __restrict__ out,
                    const unsigned* __restrict__ wcount,
                    const unsigned* __restrict__ wlist,
                    unsigned wcap) {
#pragma clang fp contract(off)
    __shared__ float sx[4][DD];
    __shared__ float sw[4][DD];
    const int lane = threadIdx.x;        // block = 1 wave
    unsigned n = *wcount;
    if (n > wcap) n = wcap;

    for (unsigned e0 = blockIdx.x * 4; e0 < n; e0 += gridDim.x * 4) {
        // gather 4 elements: lane = channel c
        unsigned idxs[4];
#pragma unroll
        for (int j = 0; j < 4; ++j) {
            unsigned e = e0 + j;
            if (e >= n) { idxs[j] = 0xFFFFFFFFu; continue; }
            unsigned idx = wlist[e];
            idxs[j] = idx;
            int px = idx % WW;
            unsigned t = idx / WW;
            int py = t % HH;  t /= HH;
            int o  = t % COUT;
            int b  = t / COUT;
            const float* xc = x  + ((size_t)(b * CIN + lane)) * LPX;
            const float* wc = Wt + (size_t)o * DD + lane * 9;
#pragma unroll
            for (int u = 0; u < 3; ++u)
#pragma unroll
                for (int v = 0; v < 3; ++v) {
                    int tp = u * 3 + v;
                    int gy = py + u - 1, gx = px + v - 1;
                    float p = ((unsigned)gy < HH && (unsigned)gx < WW)
                                  ? xc[gy * WW + gx] : 0.f;
                    sx[j][lane * 9 + tp] = p;
                    sw[j][lane * 9 + tp] = wc[tp];
                }
        }
        __syncthreads();
        if (lane < 4 && idxs[lane] != 0xFFFFFFFFu) {
            const float* px_ = sx[lane];
            const float* pw_ = sw[lane];
            float accA = 0.f, accB2 = 0.f;
            for (int d = 0; d < KC; ++d)        accA  = fmaf(px_[d], pw_[d], accA);
            for (int d = KC; d < DD; ++d)       accB2 = fmaf(px_[d], pw_[d], accB2);
            unsigned idx = idxs[lane];
            int o = (idx / LPX) % COUT;
            float zG = __fadd_rn(accA, accB2);
            float z  = __fadd_rn(zG, bias[o]);
            out[idx] = (float)dec_np(z);
        }
        __syncthreads();
    }
}

// ---- fallback (verified R9 path) ----
__global__ __launch_bounds__(256)
void np_emul_conv(const float* __restrict__ x,
                  const float* __restrict__ Wt,
                  const float* __restrict__ bias,
                  float* __restrict__ out) {
#pragma clang fp contract(off)
    int idx = blockIdx.x * 256 + threadIdx.x;
    if (idx >= TOTAL) return;
    int px = idx % WW;
    int t  = idx / WW;
    int py = t % HH;  t /= HH;
    int o  = t % COUT;
    int b  = t / COUT;
    const float* wrow = Wt + (size_t)o * DD;
    const float* xb   = x + (size_t)b * CIN * LPX;
    float accA = 0.f, accB2 = 0.f;
    for (int c = 0; c < CIN; ++c) {
        const float* xc = xb + c * LPX;
        const float* wc = wrow + c * 9;
        int dbase = c * 9;
#pragma unroll
        for (int u = 0; u < 3; ++u)
#pragma unroll
            for (int v = 0; v < 3; ++v) {
                int tp = u * 3 + v;
                int gy = py + u - 1, gx = px + v - 1;
                float p = ((unsigned)gy < HH && (unsigned)gx < WW) ? xc[gy * WW + gx] : 0.f;
                if (dbase + tp < KC) accA  = fmaf(p, wc[tp], accA);
                else                 accB2 = fmaf(p, wc[tp], accB2);
            }
    }
    float z = __fadd_rn(__fadd_rn(accA, accB2), bias[o]);
    out[idx] = (float)dec_np(z);
}

extern "C" void kernel_launch(void* const* d_in, const int* in_sizes, int n_in,
                              void* d_out, int out_size, void* d_ws, size_t ws_size,
                              hipStream_t stream) {
    const float* x  = (const float*)d_in[0];
    const float* Wt = (const float*)d_in[1];
    const float* bb = (const float*)d_in[2];
    float* out = (float*)d_out;

    const size_t WSPLIT = (size_t)COUT * DD * 2;          // 147456 B each
    const size_t XP     = (size_t)NXP * 4;                // 27.56 MB padded
    const size_t FIXED  = 2 * WSPLIT + XP + 4;

    if (ws_size >= FIXED + 65536) {
        unsigned short* Wph = (unsigned short*)d_ws;
        unsigned short* Wpl = Wph + COUT * DD;
        unsigned* xpad   = (unsigned*)((char*)d_ws + 2 * WSPLIT);
        unsigned* wcount = (unsigned*)((char*)d_ws + 2 * WSPLIT + XP);
        unsigned* wlist  = wcount + 1;
        size_t avail = (ws_size - FIXED) / 4;
        unsigned wcap = (avail > 2000000u) ? 2000000u : (unsigned)avail;

        prep_all<<<dim3(NXP / 4 / 256), dim3(256), 0, stream>>>(x, Wt, xpad, Wph, Wpl, wcount);
        conv_mfma<<<dim3(1568), dim3(256), 0, stream>>>(xpad, Wph, Wpl, bb, out,
                                                        wcount, wlist, wcap);
        exact_fix_wave<<<dim3(1024), dim3(64), 0, stream>>>(x, Wt, bb, out,
                                                            wcount, wlist, wcap);
    } else {
        np_emul_conv<<<(TOTAL + 255) / 256, 256, 0, stream>>>(x, Wt, bb, out);
    }
}

// Round 9
// 226.273 us; speedup vs baseline: 7.8147x; 1.0150x over previous
//
#include <hip/hip_runtime.h>
#include <math.h>

// B=32, Cin=64, H=W=56, Cout=128, K=3 pad=1 -> D=576, out (32,128,56,56) fp32
#define B_    32
#define CIN   64
#define HH    56
#define WW    56
#define COUT  128
#define DD    576
#define KC    384            // OpenBLAS kc split (verified R9)
#define LPX   (HH*WW)        // 3136 = 49*64
#define TOTAL (B_*COUT*LPX)
#define NX    (B_*CIN*LPX)   // 6422528
#define PW    58             // padded plane width/height
#define PPL   (PW*PW)        // 3364 words per padded channel plane
#define NXP   (B_*CIN*PPL)   // 6889472 words
#define MARGIN 4e-4f         // worst-case split-bf16 + reorder bound (validated R15-18)

typedef __attribute__((ext_vector_type(8)))  short  short8;
typedef __attribute__((ext_vector_type(16))) float  float16v;

__device__ __forceinline__ unsigned short bf16_rne(float f) {
    unsigned u = __float_as_uint(f);
    unsigned r = u + 0x7FFFu + ((u >> 16) & 1u);
    return (unsigned short)(r >> 16);
}
__device__ __forceinline__ float bf16_to_f(unsigned short h) {
    return __uint_as_float(((unsigned)h) << 16);
}

// async global->LDS staging: wave-uniform LDS base (lane l writes word l),
// per-lane global source. Tracked by vmcnt.
__device__ __forceinline__ void gload_lds4(const unsigned* g, unsigned* l) {
    __builtin_amdgcn_global_load_lds(
        (const __attribute__((address_space(1))) unsigned*)g,
        (__attribute__((address_space(3))) unsigned*)l, 4, 0, 0);
}

// ---- bit-exact numpy FLOAT_sin (npyv FMA path) — verified R9 ----
__device__ __forceinline__ float np_sinf(float x) {
#pragma clang fp contract(off)
    const float rint_cvt = 0x1.8p+23f;
    float q = __fmul_rn(x, 0x1.45f306p-1f);
    q = __fadd_rn(q, rint_cvt);
    q = __fsub_rn(q, rint_cvt);
    float r = fmaf(q, -0x1.921fb0p+0f, x);
    r = fmaf(q, -0x1.5110b4p-22f, r);
    r = fmaf(q, -0x1.846988p-48f, r);
    float r2 = __fmul_rn(r, r);
    float s = fmaf(0x1.7d3bbcp-19f, r2, -0x1.a06bbap-13f);
    s = fmaf(s, r2, 0x1.11119ap-7f);
    s = fmaf(s, r2, -0x1.555556p-3f);
    s = __fmul_rn(s, r2);
    s = fmaf(s, r, r);
    float c = fmaf(0x1.98e616p-16f, r2, -0x1.6c06dcp-10f);
    c = fmaf(c, r2, 0x1.55553cp-5f);
    c = fmaf(c, r2, -0.5f);
    c = fmaf(c, r2, 1.0f);
    int iq = (int)q;
    float res = (iq & 1) ? c : s;
    unsigned sgn = ((unsigned)(iq & 2)) << 30;
    return __uint_as_float(__float_as_uint(res) ^ sgn);
}
__device__ __forceinline__ int dec_np(float z) {
    float s = np_sinf(z);
    return (__fmul_rn(s, s) > 0.5f) ? 1 : 0;
}

// ---- merged prep (x4 vectorized): W -> fragment-major bf16 hi/lo pack,
// x -> padded 58x58 planes of (hi | lo<<16) u32 words, borders zero ----
__global__ __launch_bounds__(256)
void prep_all(const float* __restrict__ x, const float* __restrict__ W,
              unsigned* __restrict__ xpad,
              unsigned short* __restrict__ Wph, unsigned short* __restrict__ Wpl,
              unsigned* __restrict__ wcount) {
    int i4 = (blockIdx.x * 256 + threadIdx.x) * 4;
    if (i4 == 0) *wcount = 0;
    if (i4 < COUT * DD) {               // COUT*DD % 4 == 0
#pragma unroll
        for (int e = 0; e < 4; ++e) {
            int i = i4 + e;
            int o = i / DD, k = i - o * DD;
            float w = W[i];
            unsigned short h = bf16_rne(w);
            unsigned short l = bf16_rne(w - bf16_to_f(h));
            int k18 = k >> 5, kr = k & 31;
            int s = (kr >> 4) & 1, half = (kr >> 3) & 1, j = kr & 7;
            int lane = half * 32 + (o & 31);
            int ot = o >> 5;
            unsigned dst = ((((unsigned)(k18 * 4 + ot)) * 2 + s) * 64 + lane) * 8 + j;
            Wph[dst] = h;
            Wpl[dst] = l;
        }
    }
    if (i4 < NXP) {                      // NXP % 4 == 0
        unsigned vv[4];
#pragma unroll
        for (int e = 0; e < 4; ++e) {
            int i = i4 + e;
            int bc = i / PPL;
            int r  = i - bc * PPL;
            int yy = r / PW;
            int xx = r - yy * PW;
            unsigned v = 0u;
            if (yy >= 1 && yy <= HH && xx >= 1 && xx <= WW) {
                float f = x[(size_t)bc * LPX + (yy - 1) * WW + (xx - 1)];
                unsigned short h = bf16_rne(f);
                unsigned short l = bf16_rne(f - bf16_to_f(h));
                v = (unsigned)h | ((unsigned)l << 16);
            }
            vv[e] = v;
        }
        *(uint4*)(xpad + i4) = *(uint4*)vv;
    }
}

// ---- MFMA conv: 64px x 128out, 4 waves. 2-K-step PHASES (9 barriers, not
// 18) with counted vmcnt (never 0 in loop): DMA for phase p+1 issued at top
// of phase p (cover = whole phase >> HBM latency); sync waits vmcnt(4) so
// only the phase-(p+1) DMAs must retire — fresh A-loads stay in flight.
// Compiler fences pin VMEM issue order [A(2p+1)] < [DMA 16] < [A(2p+2)] so
// the count is exact. B staged once/block via global_load_lds (dedup, no
// reg round trip); A direct global->reg (L2-hot, zero duplication).
// Per-acc MFMA order identical to R5/R7/R8 -> bit-identical acc -> MARGIN valid.
#define DOFF(d) ((unsigned)((((d) / 9) * PPL) + ((((d) % 9) / 3) * PW) + (((d) % 9) % 3)))

__global__ __launch_bounds__(256, 4)
void conv_mfma(const unsigned* __restrict__ xpad,
               const unsigned short* __restrict__ Wph,
               const unsigned short* __restrict__ Wpl,
               const float* __restrict__ bias,
               float* __restrict__ out,
               unsigned* __restrict__ wcount,
               unsigned* __restrict__ wlist,
               unsigned wcap) {
    __shared__ __align__(16) unsigned Pb[2][2][32][64];   // 32KB: phase-dbuf x 2 steps

    const int tid = threadIdx.x;
    // XCD-chunked bijective swizzle (1568 = 8*196): per-XCD contiguous chunk
    // = exactly 4 batches of xpad (~3.4MB -> fits 4MB L2).
    const int bid = (blockIdx.x & 7) * 196 + (blockIdx.x >> 3);
    const int pt0 = bid * 64;            // 64-px tile, never crosses a batch

    const int w    = tid >> 6;           // o-tile (0..3)
    const int lane = tid & 63;
    const int lm   = lane & 31;
    const int half = lane >> 5;
    const int wrow = w * 512;            // this wave's 8 LDS d-rows (words)

    // DMA pixel base: lane l <-> pixel pt0+l (coalesced across the wave)
    const unsigned* xbl;
    {
        int gp = pt0 + lane;
        int br = gp / LPX;
        int pr = gp - br * LPX;
        int ypx = pr / WW;
        int xpx = pr - ypx * WW;
        xbl = xpad + (unsigned)(br * (CIN * PPL) + ypx * PW + xpx);
    }

    const uint4* wAh = (const uint4*)Wph + w * 128 + lane;
    const uint4* wAl = (const uint4*)Wpl + w * 128 + lane;

    float16v acc0, acc1;
#pragma unroll
    for (int i = 0; i < 16; ++i) { acc0[i] = 0.f; acc1[i] = 0.f; }

    uint4 AH0a, AH1a, AL0a, AL1a, AH0b, AH1b, AL0b, AL1b;

#define MFMA_(A, B, C) __builtin_amdgcn_mfma_f32_32x32x16_bf16(A, B, C, 0, 0, 0)
#define FENCE_ asm volatile("" ::: "memory");

#define LOADA_(IT, H0, H1, L0, L1)                                             \
    H0 = wAh[(IT) * 512];      H1 = wAh[(IT) * 512 + 64];                      \
    L0 = wAl[(IT) * 512];      L1 = wAl[(IT) * 512 + 64];

    // stage phase PH (steps 2PH, 2PH+1) into Pb[BUF]; wave w fills d-rows
    // w*8+i of each step (disjoint across waves); 16 DMA instr per wave
#define DMAP_(PH, BUF)                                                         \
    _Pragma("unroll") for (int s_ = 0; s_ < 2; ++s_)                           \
    _Pragma("unroll") for (int i_ = 0; i_ < 8; ++i_) {                         \
        const unsigned o0_ = DOFF((2 * (PH) + s_) * 32 + i_);                  \
        const unsigned o1_ = DOFF((2 * (PH) + s_) * 32 + 8 + i_);              \
        const unsigned o2_ = DOFF((2 * (PH) + s_) * 32 + 16 + i_);             \
        const unsigned o3_ = DOFF((2 * (PH) + s_) * 32 + 24 + i_);             \
        unsigned off_ = (w == 0) ? o0_ : (w == 1) ? o1_ : (w == 2) ? o2_ : o3_;\
        gload_lds4(xbl + off_, &Pb[BUF][s_][0][0] + wrow + i_ * 64);           \
    }

    // consume one (step, n-group): 16 LDS words -> perm -> 6 MFMAs (== R5/R7)
#define CONS1_(BUF, S, N, H0, L0, H1, L1, ACC)                                 \
    {                                                                          \
        short8 Bh0, Bl0, Bh1, Bl1;                                             \
        _Pragma("unroll") for (int m_ = 0; m_ < 4; ++m_) {                     \
            unsigned a0 = Pb[BUF][S][half * 8 + 2 * m_    ][(N) * 32 + lm];    \
            unsigned a1 = Pb[BUF][S][half * 8 + 2 * m_ + 1][(N) * 32 + lm];    \
            unsigned b0 = Pb[BUF][S][16 + half * 8 + 2 * m_    ][(N) * 32 + lm];\
            unsigned b1 = Pb[BUF][S][16 + half * 8 + 2 * m_ + 1][(N) * 32 + lm];\
            ((unsigned*)&Bh0)[m_] = __builtin_amdgcn_perm(a1, a0, 0x05040100u);\
            ((unsigned*)&Bl0)[m_] = __builtin_amdgcn_perm(a1, a0, 0x07060302u);\
            ((unsigned*)&Bh1)[m_] = __builtin_amdgcn_perm(b1, b0, 0x05040100u);\
            ((unsigned*)&Bl1)[m_] = __builtin_amdgcn_perm(b1, b0, 0x07060302u);\
        }                                                                      \
        ACC = MFMA_(*(const short8*)&H0, Bh0, ACC);                            \
        ACC = MFMA_(*(const short8*)&H0, Bl0, ACC);                            \
        ACC = MFMA_(*(const short8*)&L0, Bh0, ACC);                            \
        ACC = MFMA_(*(const short8*)&H1, Bh1, ACC);                            \
        ACC = MFMA_(*(const short8*)&H1, Bl1, ACC);                            \
        ACC = MFMA_(*(const short8*)&L1, Bh1, ACC);                            \
    }

    // counted-vmcnt sync: retire the 16 phase-(p+1) DMAs (oldest), leave the
    // 4 fresh A-loads in flight. Cross-wave: own DMAs drained before barrier.
#define SYNCN_(N)                                                              \
    asm volatile("s_waitcnt vmcnt(" #N ")" ::: "memory");                      \
    __builtin_amdgcn_s_barrier();                                              \
    asm volatile("" ::: "memory");

    // phase P (0..7): consume buf BC (steps 2P,2P+1), prefetch phase P+1->BP
#define PHASE_(P, BC, BP)                                                      \
    LOADA_(2 * (P) + 1, AH0b, AH1b, AL0b, AL1b)                                \
    FENCE_                                                                     \
    DMAP_((P) + 1, BP)                                                         \
    FENCE_                                                                     \
    CONS1_(BC, 0, 0, AH0a, AL0a, AH1a, AL1a, acc0)                             \
    CONS1_(BC, 0, 1, AH0a, AL0a, AH1a, AL1a, acc1)                             \
    CONS1_(BC, 1, 0, AH0b, AL0b, AH1b, AL1b, acc0)                             \
    CONS1_(BC, 1, 1, AH0b, AL0b, AH1b, AL1b, acc1)                             \
    FENCE_                                                                     \
    LOADA_(2 * (P) + 2, AH0a, AH1a, AL0a, AL1a)                                \
    SYNCN_(4)

    // prologue: A(0) + phase 0 staged; full drain once (outside steady loop)
    LOADA_(0, AH0a, AH1a, AL0a, AL1a)
    FENCE_
    DMAP_(0, 0)
    asm volatile("s_waitcnt vmcnt(0)" ::: "memory");
    __builtin_amdgcn_s_barrier();
    asm volatile("" ::: "memory");

    PHASE_(0, 0, 1) PHASE_(1, 1, 0) PHASE_(2, 0, 1) PHASE_(3, 1, 0)
    PHASE_(4, 0, 1) PHASE_(5, 1, 0) PHASE_(6, 0, 1) PHASE_(7, 1, 0)
    // phase 8 (consume buf0, steps 16,17): no prefetch, no sync
    LOADA_(17, AH0b, AH1b, AL0b, AL1b)
    FENCE_
    CONS1_(0, 0, 0, AH0a, AL0a, AH1a, AL1a, acc0)
    CONS1_(0, 0, 1, AH0a, AL0a, AH1a, AL1a, acc1)
    CONS1_(0, 1, 0, AH0b, AL0b, AH1b, AL1b, acc0)
    CONS1_(0, 1, 1, AH0b, AL0b, AH1b, AL1b, acc1)

#undef PHASE_
#undef SYNCN_
#undef CONS1_
#undef DMAP_
#undef LOADA_
#undef FENCE_
#undef MFMA_

#define EPI(N, ACC)                                                            \
    {                                                                          \
        const int gp0 = pt0 + (N) * 32;                                        \
        const int bpos = gp0 / LPX;                                            \
        const int pxb = gp0 - bpos * LPX + lm;                                 \
        const size_t outb = (size_t)bpos * COUT * LPX;                         \
        _Pragma("unroll") for (int reg = 0; reg < 16; ++reg) {                 \
            int o = w * 32 + 4 * half + (reg & 3) + 8 * (reg >> 2);            \
            float z = ACC[reg] + bias[o];                                      \
            float q = rintf(__fmul_rn(z, 0.63661975f));                        \
            float rr = fmaf(q, -1.5707964f, z);                                \
            float d = fabsf(fabsf(rr) - 0.78539816f);                          \
            size_t oidx = outb + (size_t)o * LPX + pxb;                        \
            out[oidx] = (float)(((int)q) & 1);                                 \
            if (d < MARGIN) {                                                  \
                unsigned pos = atomicAdd(wcount, 1u);                          \
                if (pos < wcap) wlist[pos] = (unsigned)oidx;                   \
            }                                                                  \
        }                                                                      \
    }

    EPI(0, acc0)
    EPI(1, acc1)
#undef EPI
}

// ---- wave-cooperative fixup: 1 wave per 4 elements. Lanes gather (parallel,
// BW-bound); lanes 0-3 run the bit-exact kc=384-split serial FMA chain from
// LDS (order identical to R9 -> bit-identical z). ----
__global__ __launch_bounds__(64)
void exact_fix_wave(const float* __restrict__ x,
                    const float* __restrict__ Wt,
                    const float* __restrict__ bias,
                    float* __restrict__ out,
                    const unsigned* __restrict__ wcount,
                    const unsigned* __restrict__ wlist,
                    unsigned wcap) {
#pragma clang fp contract(off)
    __shared__ float sx[4][DD];
    __shared__ float sw[4][DD];
    const int lane = threadIdx.x;        // block = 1 wave
    unsigned n = *wcount;
    if (n > wcap) n = wcap;

    for (unsigned e0 = blockIdx.x * 4; e0 < n; e0 += gridDim.x * 4) {
        // gather 4 elements: lane = channel c
        unsigned idxs[4];
#pragma unroll
        for (int j = 0; j < 4; ++j) {
            unsigned e = e0 + j;
            if (e >= n) { idxs[j] = 0xFFFFFFFFu; continue; }
            unsigned idx = wlist[e];
            idxs[j] = idx;
            int px = idx % WW;
            unsigned t = idx / WW;
            int py = t % HH;  t /= HH;
            int o  = t % COUT;
            int b  = t / COUT;
            const float* xc = x  + ((size_t)(b * CIN + lane)) * LPX;
            const float* wc = Wt + (size_t)o * DD + lane * 9;
#pragma unroll
            for (int u = 0; u < 3; ++u)
#pragma unroll
                for (int v = 0; v < 3; ++v) {
                    int tp = u * 3 + v;
                    int gy = py + u - 1, gx = px + v - 1;
                    float p = ((unsigned)gy < HH && (unsigned)gx < WW)
                                  ? xc[gy * WW + gx] : 0.f;
                    sx[j][lane * 9 + tp] = p;
                    sw[j][lane * 9 + tp] = wc[tp];
                }
        }
        __syncthreads();
        if (lane < 4 && idxs[lane] != 0xFFFFFFFFu) {
            const float* px_ = sx[lane];
            const float* pw_ = sw[lane];
            float accA = 0.f, accB2 = 0.f;
            for (int d = 0; d < KC; ++d)        accA  = fmaf(px_[d], pw_[d], accA);
            for (int d = KC; d < DD; ++d)       accB2 = fmaf(px_[d], pw_[d], accB2);
            unsigned idx = idxs[lane];
            int o = (idx / LPX) % COUT;
            float zG = __fadd_rn(accA, accB2);
            float z  = __fadd_rn(zG, bias[o]);
            out[idx] = (float)dec_np(z);
        }
        __syncthreads();
    }
}

// ---- fallback (verified R9 path) ----
__global__ __launch_bounds__(256)
void np_emul_conv(const float* __restrict__ x,
                  const float* __restrict__ Wt,
                  const float* __restrict__ bias,
                  float* __restrict__ out) {
#pragma clang fp contract(off)
    int idx = blockIdx.x * 256 + threadIdx.x;
    if (idx >= TOTAL) return;
    int px = idx % WW;
    int t  = idx / WW;
    int py = t % HH;  t /= HH;
    int o  = t % COUT;
    int b  = t / COUT;
    const float* wrow = Wt + (size_t)o * DD;
    const float* xb   = x + (size_t)b * CIN * LPX;
    float accA = 0.f, accB2 = 0.f;
    for (int c = 0; c < CIN; ++c) {
        const float* xc = xb + c * LPX;
        const float* wc = wrow + c * 9;
        int dbase = c * 9;
#pragma unroll
        for (int u = 0; u < 3; ++u)
#pragma unroll
            for (int v = 0; v < 3; ++v) {
                int tp = u * 3 + v;
                int gy = py + u - 1, gx = px + v - 1;
                float p = ((unsigned)gy < HH && (unsigned)gx < WW) ? xc[gy * WW + gx] : 0.f;
                if (dbase + tp < KC) accA  = fmaf(p, wc[tp], accA);
                else                 accB2 = fmaf(p, wc[tp], accB2);
            }
    }
    float z = __fadd_rn(__fadd_rn(accA, accB2), bias[o]);
    out[idx] = (float)dec_np(z);
}

extern "C" void kernel_launch(void* const* d_in, const int* in_sizes, int n_in,
                              void* d_out, int out_size, void* d_ws, size_t ws_size,
                              hipStream_t stream) {
    const float* x  = (const float*)d_in[0];
    const float* Wt = (const float*)d_in[1];
    const float* bb = (const float*)d_in[2];
    float* out = (float*)d_out;

    const size_t WSPLIT = (size_t)COUT * DD * 2;          // 147456 B each
    const size_t XP     = (size_t)NXP * 4;                // 27.56 MB padded
    const size_t FIXED  = 2 * WSPLIT + XP + 4;

    if (ws_size >= FIXED + 65536) {
        unsigned short* Wph = (unsigned short*)d_ws;
        unsigned short* Wpl = Wph + COUT * DD;
        unsigned* xpad   = (unsigned*)((char*)d_ws + 2 * WSPLIT);
        unsigned* wcount = (unsigned*)((char*)d_ws + 2 * WSPLIT + XP);
        unsigned* wlist  = wcount + 1;
        size_t avail = (ws_size - FIXED) / 4;
        unsigned wcap = (avail > 2000000u) ? 2000000u : (unsigned)avail;

        prep_all<<<dim3(NXP / 4 / 256), dim3(256), 0, stream>>>(x, Wt, xpad, Wph, Wpl, wcount);
        conv_mfma<<<dim3(1568), dim3(256), 0, stream>>>(xpad, Wph, Wpl, bb, out,
                                                        wcount, wlist, wcap);
        exact_fix_wave<<<dim3(1024), dim3(64), 0, stream>>>(x, Wt, bb, out,
                                                            wcount, wlist, wcap);
    } else {
        np_emul_conv<<<(TOTAL + 255) / 256, 256, 0, stream>>>(x, Wt, bb, out);
    }
}